// Round 12
// baseline (1492.308 us; speedup 1.0000x reference)
//
#include <hip/hip_runtime.h>

typedef unsigned int u32;
typedef unsigned short u16;
typedef unsigned long long u64;

using short8 = __attribute__((ext_vector_type(8))) short;
using f32x4  = __attribute__((ext_vector_type(4))) float;

// ---------- bf16 helpers ----------
__device__ __forceinline__ u32 f2bf(float f) {  // RTN-even
    u32 u = __float_as_uint(f);
    return (u + 0x7fffu + ((u >> 16) & 1u)) >> 16;
}
__device__ __forceinline__ u32 pk(float a, float b) {
    return f2bf(a) | (f2bf(b) << 16);
}
__device__ __forceinline__ u32 f2bf_fast(float f) {  // round-half-up, 2 inst
    return (__float_as_uint(f) + 0x8000u) >> 16;
}
__device__ __forceinline__ u32 pk_fast(float a, float b) {
    return f2bf_fast(a) | (f2bf_fast(b) << 16);
}
__device__ __forceinline__ float bflo(u32 u) { return __uint_as_float(u << 16); }
__device__ __forceinline__ float bfhi(u32 u) { return __uint_as_float(u & 0xffff0000u); }
__device__ __forceinline__ float bfu(u16 u) { return __uint_as_float(((u32)u) << 16); }

// packed-bf16 HW atomic: adds v into the bf16 element at p+(c_odd); 0 into the other half.
__device__ __forceinline__ void atomic_add_bf16(u16* p, int c_odd, float v) {
    u32 dat = f2bf(v) << (c_odd << 4);
    asm volatile("global_atomic_pk_add_bf16 %0, %1, off" :: "v"((u64)p), "v"(dat) : "memory");
}

union U8 { u32 u[4]; short8 v; };

// ---------- input projection + LayerNorm + ReLU (wave per node), bf16 state; zeros agg ----------
__global__ void k_input_proj(const float* __restrict__ x, const float* __restrict__ in_w,
                             const float* __restrict__ in_b, const float* __restrict__ ln_g,
                             const float* __restrict__ ln_b, u16* __restrict__ hbf,
                             u16* __restrict__ aggb, int n_nodes) {
    const int lane = threadIdx.x & 63;
    const int node = blockIdx.x * 4 + (threadIdx.x >> 6);
    if (node >= n_nodes) return;
    aggb[(size_t)node * 64 + lane] = 0;  // layer-0 agg zero (ws is re-poisoned every call)
    float acc = in_b[lane];
#pragma unroll
    for (int k = 0; k < 4; ++k) acc = fmaf(x[node * 4 + k], in_w[k * 64 + lane], acc);
    float s = acc;
#pragma unroll
    for (int off = 32; off > 0; off >>= 1) s += __shfl_xor(s, off);
    float mu = s * (1.f / 64.f);
    float d = acc - mu;
    float vs = d * d;
#pragma unroll
    for (int off = 32; off > 0; off >>= 1) vs += __shfl_xor(vs, off);
    float inv = rsqrtf(vs * (1.f / 64.f) + 1e-5f);
    float hv = fmaxf(d * inv * ln_g[lane] + ln_b[lane], 0.f);
    hbf[(size_t)node * 64 + lane] = (u16)f2bf(hv);
}

// ---------- (type,dst)-sort: histogram(+key), scan, dst-fill, partitioned scatter ----------
__global__ void k_hist(const int* __restrict__ dst, const int* __restrict__ ety,
                       int* __restrict__ cnt, int* __restrict__ key, int M, int N) {
    int i = blockIdx.x * 256 + threadIdx.x;
    if (i < M) {
        int k = (ety[i] & 1) * N + dst[i];
        key[i] = k;
        atomicAdd(&cnt[k], 1);
    }
}

__global__ void k_scan1(int* __restrict__ data, int* __restrict__ part, int N) {
    __shared__ int s[1024];
    const int t = threadIdx.x;
    const int i = blockIdx.x * 1024 + t;
    int v = (i < N) ? data[i] : 0;
    s[t] = v;
    __syncthreads();
#pragma unroll
    for (int d = 1; d < 1024; d <<= 1) {
        int x = (t >= d) ? s[t - d] : 0;
        __syncthreads();
        s[t] += x;
        __syncthreads();
    }
    if (i < N) data[i] = s[t] - v;  // exclusive
    if (t == 1023) part[blockIdx.x] = s[1023];
}

__global__ void k_scan2(int* __restrict__ part, int nb) {
    const int l = threadIdx.x & 63;
    int base = 0;
    for (int s = 0; s < nb; s += 64) {
        int i = s + l;
        int orig = (i < nb) ? part[i] : 0;
        int x = orig;
#pragma unroll
        for (int off = 1; off < 64; off <<= 1) {
            int t = __shfl_up(x, off);
            if (l >= off) x += t;
        }
        if (i < nb) part[i] = base + x - orig;  // exclusive
        base += __shfl(x, 63);
    }
}

__global__ void k_scan3(int* __restrict__ data, const int* __restrict__ part, int N,
                        int saveIdx, int* __restrict__ slot) {
    int i = blockIdx.x * 1024 + threadIdx.x;
    if (i < N) {
        int v = data[i] + part[blockIdx.x];
        data[i] = v;
        if (i == saveIdx) slot[0] = v;  // T0 = # of type-0 edges
    }
}

__global__ void k_filldst(const int* __restrict__ off, int* __restrict__ dstP,
                          int NB, int N, int M) {
    int b = blockIdx.x * 256 + threadIdx.x;
    if (b >= NB) return;
    int s = off[b];
    int e = (b + 1 < NB) ? off[b + 1] : M;
    int d = (b >= N) ? b - N : b;
    for (int p = s; p < e; ++p) dstP[p] = d;
}

// XCD-partitioned scatter (round-8 win): group g commits only its dst partition.
__global__ void k_scatter(const int* __restrict__ src, const int* __restrict__ key,
                          int* __restrict__ cursor, int* __restrict__ srcP,
                          int M, int N, int nd8) {
    const int g = blockIdx.x & 7;
    const int nb = gridDim.x >> 3;
    const int bi = blockIdx.x >> 3;
    for (int e = bi * 256 + threadIdx.x; e < M; e += nb * 256) {
        int k = key[e];
        int d = (k >= N) ? k - N : k;
        if (d / nd8 == g) {
            int pos = atomicAdd(&cursor[k], 1);
            srcP[pos] = src[e] & 0x3FFFFFFF;
        }
    }
}

// ---------- edge message MLP: one tile per wave, zero barriers, deep pipeline ----------
// Round-8 structure (2 blocks/CU, B-frags in registers) + fused next-tile gathers
// inside layer-1 + 2-deep meta pipeline. agg is bf16; scatter-add uses HW
// global_atomic_pk_add_bf16 (one half active, 0 in the other — exact).
__global__ __launch_bounds__(256, 2) void k_edge_mlp(
    const u16* __restrict__ hbf, const int* __restrict__ srcP, const int* __restrict__ dstP,
    const int* __restrict__ t0p, const float* __restrict__ w1, const float* __restrict__ b1,
    const float* __restrict__ w2, const float* __restrict__ b2,
    u16* __restrict__ agg, int M) {
    __shared__ u16 sHid[4][4608];   // per-wave hidden [row][col] stride 72
    __shared__ u16 sMsg[4][4864];   // per-wave msg    [col][edge] stride 76 (disjoint)

    const int tid = threadIdx.x;
    const int l = tid & 63, wv = tid >> 6;
    const int l15 = l & 15, quad = l >> 4;
    const f32x4 vz = {0.f, 0.f, 0.f, 0.f};

    const int T0 = *t0p;
    const int half = gridDim.x >> 1;
    const int ty = (blockIdx.x >= half) ? 1 : 0;
    const int bi = ty ? (int)blockIdx.x - half : (int)blockIdx.x;

    const int n_tiles = (M + 63) >> 6;
    const int tlo = ty ? (T0 >> 6) : 0;
    const int thi = ty ? n_tiles : ((T0 + 63) >> 6);
    const int lo = ty ? T0 : 0;
    const int hi = ty ? M : T0;
    const int range = thi - tlo;
    const int per = (range + half - 1) / half;
    const int c0 = tlo + bi * per;
    const int c1 = min(c0 + per, thi);

    // ---- register B fragments + biases for this block's type (static idx) ----
    short8 Bf1[4][4], Bf2[2][4];
    float b1r[4], b2r[4];
#pragma unroll
    for (int ni = 0; ni < 4; ++ni) {
        const int c = ni * 16 + l15;
        b1r[ni] = b1[ty * 64 + c];
        b2r[ni] = b2[ty * 64 + c];
#pragma unroll
        for (int s = 0; s < 4; ++s) {
            U8 tmp;
            const float* wp = w1 + (size_t)ty * 8192 + (size_t)(s * 32 + quad * 8) * 64 + c;
#pragma unroll
            for (int jp = 0; jp < 4; ++jp) tmp.u[jp] = pk(wp[(2 * jp) * 64], wp[(2 * jp + 1) * 64]);
            Bf1[s][ni] = tmp.v;
        }
#pragma unroll
        for (int s = 0; s < 2; ++s) {
            U8 tmp;
            const float* wp = w2 + (size_t)ty * 4096 + (size_t)(s * 32 + quad * 8) * 64 + c;
#pragma unroll
            for (int jp = 0; jp < 4; ++jp) tmp.u[jp] = pk(wp[(2 * jp) * 64], wp[(2 * jp + 1) * 64]);
            Bf2[s][ni] = tmp.v;
        }
    }

    u16* hid = sHid[wv];
    u16* msg = sMsg[wv];

    int t = c0 + wv;
    int mdc = -1;            // dst vector for current tile (lane l = edge l)
    int msn = 0, mdn = -1;   // meta for tile t+4
    short8 a1[4][4];
    if (t < c1) {  // prologue: tile-t meta + gathers, tile-(t+4) meta
        int ec = min((t << 6) + l, M - 1);
        int ms = srcP[ec];
        mdc = dstP[ec];
#pragma unroll
        for (int mi = 0; mi < 4; ++mi) {
            int rs = __shfl(ms, mi * 16 + l15);
            int rd = __shfl(mdc, mi * 16 + l15);
#pragma unroll
            for (int s = 0; s < 4; ++s) {
                const int row = (s < 2) ? rs : rd;
                a1[mi][s] = *(const short8*)(hbf + (size_t)row * 64 + (s & 1) * 32 + quad * 8);
            }
        }
        int ecn = min(((t + 4) << 6) + l, M - 1);
        msn = srcP[ecn];
        mdn = dstP[ecn];
    }

    for (; t < c1; t += 4) {
        const int base = t << 6;
        // meta prefetch for t+8 (clamped; harmless past end)
        const int ecf = min(((t + 8) << 6) + l, M - 1);
        const int msf = srcP[ecf];
        const int mdf = dstP[ecf];

        // ---- layer 1 with fused next-tile (t+4) A-gathers ----
#pragma unroll
        for (int mi = 0; mi < 4; ++mi) {
            f32x4 acc[4] = {vz, vz, vz, vz};
#pragma unroll
            for (int s = 0; s < 4; ++s)
#pragma unroll
                for (int ni = 0; ni < 4; ++ni)
                    acc[ni] = __builtin_amdgcn_mfma_f32_16x16x32_bf16(a1[mi][s], Bf1[s][ni], acc[ni], 0, 0, 0);
            // a1[mi] consumed -> issue next tile's gathers for this mi now
            {
                int rs = __shfl(msn, mi * 16 + l15);
                int rd = __shfl(mdn, mi * 16 + l15);
#pragma unroll
                for (int s = 0; s < 4; ++s) {
                    const int row = (s < 2) ? rs : rd;
                    a1[mi][s] = *(const short8*)(hbf + (size_t)row * 64 + (s & 1) * 32 + quad * 8);
                }
            }
#pragma unroll
            for (int ni = 0; ni < 4; ++ni) {
                const int c = ni * 16 + l15;
#pragma unroll
                for (int r = 0; r < 4; ++r) {
                    float hv = fmaxf(acc[ni][r] + b1r[ni], 0.f);
                    hid[(mi * 16 + quad * 4 + r) * 72 + c] = (u16)f2bf_fast(hv);
                }
            }
        }

        // ---- layer 2 ----
#pragma unroll
        for (int mi = 0; mi < 4; ++mi) {
            short8 a2a = *(const short8*)(hid + (mi * 16 + l15) * 72 + quad * 8);
            short8 a2b = *(const short8*)(hid + (mi * 16 + l15) * 72 + 32 + quad * 8);
#pragma unroll
            for (int ni = 0; ni < 4; ++ni) {
                f32x4 tt = __builtin_amdgcn_mfma_f32_16x16x32_bf16(a2a, Bf2[0][ni], vz, 0, 0, 0);
                f32x4 m2 = __builtin_amdgcn_mfma_f32_16x16x32_bf16(a2b, Bf2[1][ni], tt, 0, 0, 0);
                const int c = ni * 16 + l15;
                const int e0 = mi * 16 + quad * 4;
                const float bb = b2r[ni];
                uint2 w;
                w.x = pk_fast(m2[0] + bb, m2[1] + bb);
                w.y = pk_fast(m2[2] + bb, m2[3] + bb);
                *(uint2*)(msg + c * 76 + e0) = w;  // 8B-aligned (c*152 + e0*2)
            }
        }

        // ---- run-reduction: ballot mask in SGPRs, one pk-bf16 atomic per (run, col) ----
        {
            int eg = base + l;
            int dvz = (eg >= lo && eg < hi) ? mdc : -1;
            int dprev = __shfl_up(dvz, 1);
            u64 mask = __ballot((l == 0) || (dvz != dprev));
            float a = 0.f;
#pragma unroll
            for (int i = 0; i < 64; i += 4) {
                uint2 pr = *(const uint2*)(msg + l * 76 + i);
                float v0 = bflo(pr.x), v1 = bfhi(pr.x), v2 = bflo(pr.y), v3 = bfhi(pr.y);
#define RR_STEP(ii, vv)                                                              \
                a += (vv);                                                           \
                if ((ii) == 63 || ((mask >> ((ii) + 1)) & 1ull)) {                   \
                    int dd = __builtin_amdgcn_readlane(dvz, (ii));                   \
                    if (dd >= 0)                                                     \
                        atomic_add_bf16(agg + (size_t)dd * 64 + (l & ~1), l & 1, a); \
                    a = 0.f;                                                         \
                }
                RR_STEP(i, v0)
                RR_STEP(i + 1, v1)
                RR_STEP(i + 2, v2)
                RR_STEP(i + 3, v3)
#undef RR_STEP
            }
        }
        // rotate meta pipeline
        mdc = mdn;
        msn = msf;
        mdn = mdf;
    }
}

// ---------- GRU via MFMA (bf16 state + bf16 agg), fused readout on last layer ----------
__global__ __launch_bounds__(256, 2) void k_gru_gemm(
    u16* __restrict__ aggb, u16* __restrict__ hbf,
    const float* __restrict__ wi, const float* __restrict__ wh,
    const float* __restrict__ bi, const float* __restrict__ bh, int n_nodes, int last,
    const float* __restrict__ ro_w1, const float* __restrict__ ro_b1,
    const float* __restrict__ ro_w2, const float* __restrict__ ro_b2,
    const float* __restrict__ x, const int* __restrict__ node_type, float* __restrict__ out) {
    extern __shared__ u16 smem[];
    u16* sRZ = smem;                 // 128 cols x stride 136 (r|z), K=128=[agg|h]
    u16* sIN = smem + 128 * 136;     // 64 cols x stride 72, K=64 (agg)
    u16* sHN = sIN + 64 * 72;        // 64 cols x stride 72, K=64 (h)
    u16* sTR = sHN + 64 * 72;        // 4 waves x (16 nodes x stride 72) output transpose
    u16* sRO = sTR + 4 * 16 * 72;    // readout W1, 64 cols x stride 72

    const int tid = threadIdx.x;
    const int l = tid & 63, wv = tid >> 6;
    const int l15 = l & 15, quad = l >> 4;
    const f32x4 vz = {0.f, 0.f, 0.f, 0.f};
    const short8 z8 = {0, 0, 0, 0, 0, 0, 0, 0};

    // stage weights (coalesced: consecutive lanes -> consecutive columns)
    for (int u = tid; u < 128 * 64; u += 256) {
        int c = u & 127, k0 = (u >> 7) * 2;
        float v0 = (k0 < 64) ? wi[k0 * 192 + c] : wh[(k0 - 64) * 192 + c];
        float v1 = (k0 < 64) ? wi[(k0 + 1) * 192 + c] : wh[(k0 + 1 - 64) * 192 + c];
        *(u32*)(sRZ + c * 136 + k0) = pk(v0, v1);
    }
    for (int u = tid; u < 64 * 32; u += 256) {
        int c = u & 63, k0 = (u >> 6) * 2;
        *(u32*)(sIN + c * 72 + k0) = pk(wi[k0 * 192 + 128 + c], wi[(k0 + 1) * 192 + 128 + c]);
        *(u32*)(sHN + c * 72 + k0) = pk(wh[k0 * 192 + 128 + c], wh[(k0 + 1) * 192 + 128 + c]);
        *(u32*)(sRO + c * 72 + k0) = pk(ro_w1[k0 * 64 + c], ro_w1[(k0 + 1) * 64 + c]);
    }
    float bR[4], bZ[4], bI[4], bH[4], b1v[4], w2v[4];
#pragma unroll
    for (int nt = 0; nt < 4; ++nt) {
        int j = nt * 16 + l15;
        bR[nt] = bi[j] + bh[j];
        bZ[nt] = bi[64 + j] + bh[64 + j];
        bI[nt] = bi[128 + j];
        bH[nt] = bh[128 + j];
        b1v[nt] = ro_b1[j];
        w2v[nt] = ro_w2[j];
    }
    const float b2s = ro_b2[0];
    __syncthreads();  // the only barrier

    u16* tr = sTR + wv * (16 * 72);
    const int n_tiles = (n_nodes + 15) >> 4;
    // XCD-chunked node ranges: group g owns a contiguous eighth of the tiles
    const int g = blockIdx.x & 7, jb = blockIdx.x >> 3, nbg = gridDim.x >> 3;
    const int per8 = (n_tiles + 7) >> 3;
    const int glo = g * per8, ghi = min(glo + per8, n_tiles);
    for (int tile = glo + jb * 4 + wv; tile < ghi; tile += nbg * 4) {
        const int nb = tile << 4;
        const int arow = nb + l15;
        const int rowc = (arow < n_nodes) ? arow : (n_nodes - 1);
        short8 aA[2], aH[2];
#pragma unroll
        for (int s = 0; s < 2; ++s) {
            aA[s] = *(const short8*)(aggb + (size_t)rowc * 64 + s * 32 + quad * 8);
            aH[s] = *(const short8*)(hbf + (size_t)rowc * 64 + s * 32 + quad * 8);
        }
        // re-zero agg for the next layer (tile rows exclusively ours; skip on last)
        if (!last && arow < n_nodes) {
#pragma unroll
            for (int s = 0; s < 2; ++s)
                *(short8*)(aggb + (size_t)rowc * 64 + s * 32 + quad * 8) = z8;
        }
        f32x4 D[16];
#pragma unroll
        for (int i = 0; i < 16; ++i) D[i] = vz;
#pragma unroll
        for (int nt = 0; nt < 8; ++nt) {
            const u16* bp = sRZ + (nt * 16 + l15) * 136 + quad * 8;
            D[nt] = __builtin_amdgcn_mfma_f32_16x16x32_bf16(aA[0], *(const short8*)bp, D[nt], 0, 0, 0);
            D[nt] = __builtin_amdgcn_mfma_f32_16x16x32_bf16(aA[1], *(const short8*)(bp + 32), D[nt], 0, 0, 0);
            D[nt] = __builtin_amdgcn_mfma_f32_16x16x32_bf16(aH[0], *(const short8*)(bp + 64), D[nt], 0, 0, 0);
            D[nt] = __builtin_amdgcn_mfma_f32_16x16x32_bf16(aH[1], *(const short8*)(bp + 96), D[nt], 0, 0, 0);
        }
#pragma unroll
        for (int nt = 0; nt < 4; ++nt) {
            const u16* ip = sIN + (nt * 16 + l15) * 72 + quad * 8;
            D[8 + nt] = __builtin_amdgcn_mfma_f32_16x16x32_bf16(aA[0], *(const short8*)ip, D[8 + nt], 0, 0, 0);
            D[8 + nt] = __builtin_amdgcn_mfma_f32_16x16x32_bf16(aA[1], *(const short8*)(ip + 32), D[8 + nt], 0, 0, 0);
            const u16* hp = sHN + (nt * 16 + l15) * 72 + quad * 8;
            D[12 + nt] = __builtin_amdgcn_mfma_f32_16x16x32_bf16(aH[0], *(const short8*)hp, D[12 + nt], 0, 0, 0);
            D[12 + nt] = __builtin_amdgcn_mfma_f32_16x16x32_bf16(aH[1], *(const short8*)(hp + 32), D[12 + nt], 0, 0, 0);
        }
        // combine -> per-wave LDS transpose tile (u16), then coalesced global stores
#pragma unroll
        for (int nt = 0; nt < 4; ++nt) {
            const int j = nt * 16 + l15;
#pragma unroll
            for (int r = 0; r < 4; ++r) {
                const int nd = nb + quad * 4 + r;
                float rsv = D[nt][r] + bR[nt];
                float zsv = D[4 + nt][r] + bZ[nt];
                float inv = D[8 + nt][r] + bI[nt];
                float hnv = D[12 + nt][r] + bH[nt];
                float rr = 1.f / (1.f + __expf(-rsv));
                float zz = 1.f / (1.f + __expf(-zsv));
                float nn = tanhf(fmaf(rr, hnv, inv));
                float hv = (nd < n_nodes) ? bfu(hbf[(size_t)nd * 64 + j]) : 0.f;
                float nh = (1.f - zz) * nn + zz * hv;
                tr[(quad * 4 + r) * 72 + j] = (u16)f2bf(nh);
            }
        }
        {   // coalesced write-back: lane covers 32 contiguous bytes of one node
            const int nd = nb + (l >> 2);
            if (nd < n_nodes) {
                const u16* sp = tr + (l >> 2) * 72 + (l & 3) * 16;
                uint4 va = *(const uint4*)sp;
                uint4 vb = *(const uint4*)(sp + 8);
                u16* dp = hbf + (size_t)nd * 64 + (l & 3) * 16;
                *(uint4*)dp = va;
                *(uint4*)(dp + 8) = vb;
            }
        }
        if (last) {  // fused readout: tr holds this tile's final h (same-wave DS order)
            short8 ar0 = *(const short8*)(tr + l15 * 72 + quad * 8);
            short8 ar1 = *(const short8*)(tr + l15 * 72 + 32 + quad * 8);
            float p[4] = {0.f, 0.f, 0.f, 0.f};
#pragma unroll
            for (int nt = 0; nt < 4; ++nt) {
                const u16* bp = sRO + (nt * 16 + l15) * 72 + quad * 8;
                f32x4 acc = __builtin_amdgcn_mfma_f32_16x16x32_bf16(ar0, *(const short8*)bp, vz, 0, 0, 0);
                acc = __builtin_amdgcn_mfma_f32_16x16x32_bf16(ar1, *(const short8*)(bp + 32), acc, 0, 0, 0);
#pragma unroll
                for (int r = 0; r < 4; ++r)
                    p[r] += fmaxf(acc[r] + b1v[nt], 0.f) * w2v[nt];
            }
#pragma unroll
            for (int off = 1; off < 16; off <<= 1)
#pragma unroll
                for (int r = 0; r < 4; ++r) p[r] += __shfl_xor(p[r], off);
            if (l15 == 0) {
#pragma unroll
                for (int r = 0; r < 4; ++r) {
                    const int nd = nb + quad * 4 + r;
                    if (nd < n_nodes) {
                        float o = p[r] + b2s;
                        out[nd] = (node_type[nd] == 0) ? (x[nd * 4] + o) : 0.f;
                    }
                }
            }
        }
    }
}

extern "C" void kernel_launch(void* const* d_in, const int* in_sizes, int n_in, void* d_out,
                              int out_size, void* d_ws, size_t ws_size, hipStream_t stream) {
    const float* x = (const float*)d_in[0];
    const int* node_type = (const int*)d_in[1];
    const int* edge_index = (const int*)d_in[2];
    const int* edge_type = (const int*)d_in[3];
    const float* in_w = (const float*)d_in[4];
    const float* in_b = (const float*)d_in[5];
    const float* ln_g = (const float*)d_in[6];
    const float* ln_b = (const float*)d_in[7];
    const float* mlp_w1 = (const float*)d_in[8];
    const float* mlp_b1 = (const float*)d_in[9];
    const float* mlp_w2 = (const float*)d_in[10];
    const float* mlp_b2 = (const float*)d_in[11];
    const float* gru_wi = (const float*)d_in[12];
    const float* gru_wh = (const float*)d_in[13];
    const float* gru_bi = (const float*)d_in[14];
    const float* gru_bh = (const float*)d_in[15];
    const float* ro_w1 = (const float*)d_in[16];
    const float* ro_b1 = (const float*)d_in[17];
    const float* ro_w2 = (const float*)d_in[18];
    const float* ro_b2 = (const float*)d_in[19];

    const int N = in_sizes[1];  // nodes
    const int M = in_sizes[3];  // edges
    const int* src = edge_index;
    const int* dst = edge_index + M;

    // ws: aggb (N*128B) | hbf (N*128B) | off (2N*4) | part (4KB) | srcP | dstP | key
    char* wsb = (char*)d_ws;
    u16* aggb = (u16*)wsb;
    u16* hbf = (u16*)(wsb + (size_t)N * 128);
    int* off = (int*)(wsb + (size_t)N * 256);
    int* part = (int*)(wsb + (size_t)N * 256 + (size_t)2 * N * 4);
    int* srcP = (int*)(wsb + (size_t)N * 256 + (size_t)2 * N * 4 + 4096);
    int* dstP = srcP + M;
    int* key = dstP + M;
    int* t0slot = part + 1000;

    const int NB = 2 * N;
    const int nb = (NB + 1023) / 1024;
    const int nd8 = (N + 7) / 8;

    // build (type,dst)-sorted edge permutation (reused by all 3 layers)
    hipMemsetAsync(off, 0, (size_t)NB * sizeof(int), stream);
    k_hist<<<(M + 255) / 256, 256, 0, stream>>>(dst, edge_type, off, key, M, N);
    k_scan1<<<nb, 1024, 0, stream>>>(off, part, NB);
    k_scan2<<<1, 64, 0, stream>>>(part, nb);
    k_scan3<<<nb, 1024, 0, stream>>>(off, part, NB, N, t0slot);
    k_filldst<<<(NB + 255) / 256, 256, 0, stream>>>(off, dstP, NB, N, M);  // before cursors mutate
    k_scatter<<<2048, 256, 0, stream>>>(src, key, off, srcP, M, N, nd8);

    k_input_proj<<<(N + 3) / 4, 256, 0, stream>>>(x, in_w, in_b, ln_g, ln_b, hbf, aggb, N);
    const size_t gruLds =
        (size_t)(128 * 136 + 64 * 72 + 64 * 72 + 4 * 16 * 72 + 64 * 72) * sizeof(u16);  // 71680
    for (int l = 0; l < 3; ++l) {
        k_edge_mlp<<<1024, 256, 0, stream>>>(hbf, srcP, dstP, t0slot,
                                             mlp_w1 + (size_t)l * 2 * 128 * 64,
                                             mlp_b1 + (size_t)l * 2 * 64,
                                             mlp_w2 + (size_t)l * 2 * 64 * 64,
                                             mlp_b2 + (size_t)l * 2 * 64, aggb, M);
        k_gru_gemm<<<1024, 256, gruLds, stream>>>(aggb, hbf, gru_wi + (size_t)l * 64 * 192,
                                                  gru_wh + (size_t)l * 64 * 192,
                                                  gru_bi + (size_t)l * 192, gru_bh + (size_t)l * 192,
                                                  N, (l == 2) ? 1 : 0,
                                                  ro_w1, ro_b1, ro_w2, ro_b2,
                                                  x, node_type, (float*)d_out);
    }
}

// Round 13
// 743.366 us; speedup vs baseline: 2.0075x; 2.0075x over previous
//
#include <hip/hip_runtime.h>

typedef unsigned int u32;
typedef unsigned short u16;
typedef unsigned long long u64;

using short8 = __attribute__((ext_vector_type(8))) short;
using f32x4  = __attribute__((ext_vector_type(4))) float;

// ---------- bf16 helpers ----------
__device__ __forceinline__ u32 f2bf(float f) {  // RTN-even
    u32 u = __float_as_uint(f);
    return (u + 0x7fffu + ((u >> 16) & 1u)) >> 16;
}
__device__ __forceinline__ u32 pk(float a, float b) {
    return f2bf(a) | (f2bf(b) << 16);
}
__device__ __forceinline__ u32 f2bf_fast(float f) {  // round-half-up, 2 inst
    return (__float_as_uint(f) + 0x8000u) >> 16;
}
__device__ __forceinline__ u32 pk_fast(float a, float b) {
    return f2bf_fast(a) | (f2bf_fast(b) << 16);
}
__device__ __forceinline__ float bflo(u32 u) { return __uint_as_float(u << 16); }
__device__ __forceinline__ float bfhi(u32 u) { return __uint_as_float(u & 0xffff0000u); }
__device__ __forceinline__ float bfu(u16 u) { return __uint_as_float(((u32)u) << 16); }

union U8 { u32 u[4]; short8 v; };

// ---------- input projection + LayerNorm + ReLU (wave per node); zeros agg (fp32) ----------
__global__ void k_input_proj(const float* __restrict__ x, const float* __restrict__ in_w,
                             const float* __restrict__ in_b, const float* __restrict__ ln_g,
                             const float* __restrict__ ln_b, u16* __restrict__ hbf,
                             float* __restrict__ agg, int n_nodes) {
    const int lane = threadIdx.x & 63;
    const int node = blockIdx.x * 4 + (threadIdx.x >> 6);
    if (node >= n_nodes) return;
    agg[(size_t)node * 64 + lane] = 0.f;  // layer-0 agg zero (ws re-poisoned every call)
    float acc = in_b[lane];
#pragma unroll
    for (int k = 0; k < 4; ++k) acc = fmaf(x[node * 4 + k], in_w[k * 64 + lane], acc);
    float s = acc;
#pragma unroll
    for (int off = 32; off > 0; off >>= 1) s += __shfl_xor(s, off);
    float mu = s * (1.f / 64.f);
    float d = acc - mu;
    float vs = d * d;
#pragma unroll
    for (int off = 32; off > 0; off >>= 1) vs += __shfl_xor(vs, off);
    float inv = rsqrtf(vs * (1.f / 64.f) + 1e-5f);
    float hv = fmaxf(d * inv * ln_g[lane] + ln_b[lane], 0.f);
    hbf[(size_t)node * 64 + lane] = (u16)f2bf(hv);
}

// ---------- (type,dst)-sort: histogram(+key), scan, dst-fill, partitioned scatter ----------
__global__ void k_hist(const int* __restrict__ dst, const int* __restrict__ ety,
                       int* __restrict__ cnt, int* __restrict__ key, int M, int N) {
    int i = blockIdx.x * 256 + threadIdx.x;
    if (i < M) {
        int k = (ety[i] & 1) * N + dst[i];
        key[i] = k;
        atomicAdd(&cnt[k], 1);
    }
}

__global__ void k_scan1(int* __restrict__ data, int* __restrict__ part, int N) {
    __shared__ int s[1024];
    const int t = threadIdx.x;
    const int i = blockIdx.x * 1024 + t;
    int v = (i < N) ? data[i] : 0;
    s[t] = v;
    __syncthreads();
#pragma unroll
    for (int d = 1; d < 1024; d <<= 1) {
        int x = (t >= d) ? s[t - d] : 0;
        __syncthreads();
        s[t] += x;
        __syncthreads();
    }
    if (i < N) data[i] = s[t] - v;  // exclusive
    if (t == 1023) part[blockIdx.x] = s[1023];
}

__global__ void k_scan2(int* __restrict__ part, int nb) {
    const int l = threadIdx.x & 63;
    int base = 0;
    for (int s = 0; s < nb; s += 64) {
        int i = s + l;
        int orig = (i < nb) ? part[i] : 0;
        int x = orig;
#pragma unroll
        for (int off = 1; off < 64; off <<= 1) {
            int t = __shfl_up(x, off);
            if (l >= off) x += t;
        }
        if (i < nb) part[i] = base + x - orig;  // exclusive
        base += __shfl(x, 63);
    }
}

__global__ void k_scan3(int* __restrict__ data, const int* __restrict__ part, int N,
                        int saveIdx, int* __restrict__ slot) {
    int i = blockIdx.x * 1024 + threadIdx.x;
    if (i < N) {
        int v = data[i] + part[blockIdx.x];
        data[i] = v;
        if (i == saveIdx) slot[0] = v;  // T0 = # of type-0 edges
    }
}

__global__ void k_filldst(const int* __restrict__ off, int* __restrict__ dstP,
                          int NB, int N, int M) {
    int b = blockIdx.x * 256 + threadIdx.x;
    if (b >= NB) return;
    int s = off[b];
    int e = (b + 1 < NB) ? off[b + 1] : M;
    int d = (b >= N) ? b - N : b;
    for (int p = s; p < e; ++p) dstP[p] = d;
}

// XCD-partitioned scatter (round-8 win): group g commits only its dst partition.
__global__ void k_scatter(const int* __restrict__ src, const int* __restrict__ key,
                          int* __restrict__ cursor, int* __restrict__ srcP,
                          int M, int N, int nd8) {
    const int g = blockIdx.x & 7;
    const int nb = gridDim.x >> 3;
    const int bi = blockIdx.x >> 3;
    for (int e = bi * 256 + threadIdx.x; e < M; e += nb * 256) {
        int k = key[e];
        int d = (k >= N) ? k - N : k;
        if (d / nd8 == g) {
            int pos = atomicAdd(&cursor[k], 1);
            srcP[pos] = src[e] & 0x3FFFFFFF;
        }
    }
}

// ---------- edge message MLP: one tile per wave, zero barriers, deep pipeline ----------
// Round-11 known-good (113 us): 2 blocks/CU, B-frags in registers, fused next-tile
// gathers inside layer-1, 2-deep meta pipeline, fp32 agg + unsafeAtomicAdd
// (native L2-side f32 atomic — pk_add_bf16 was 3x slower, round-12 regression).
__global__ __launch_bounds__(256, 2) void k_edge_mlp(
    const u16* __restrict__ hbf, const int* __restrict__ srcP, const int* __restrict__ dstP,
    const int* __restrict__ t0p, const float* __restrict__ w1, const float* __restrict__ b1,
    const float* __restrict__ w2, const float* __restrict__ b2,
    float* __restrict__ agg, int M) {
    __shared__ u16 sHid[4][4608];   // per-wave hidden [row][col] stride 72
    __shared__ u16 sMsg[4][4864];   // per-wave msg    [col][edge] stride 76 (disjoint)

    const int tid = threadIdx.x;
    const int l = tid & 63, wv = tid >> 6;
    const int l15 = l & 15, quad = l >> 4;
    const f32x4 vz = {0.f, 0.f, 0.f, 0.f};

    const int T0 = *t0p;
    const int half = gridDim.x >> 1;
    const int ty = (blockIdx.x >= half) ? 1 : 0;
    const int bi = ty ? (int)blockIdx.x - half : (int)blockIdx.x;

    const int n_tiles = (M + 63) >> 6;
    const int tlo = ty ? (T0 >> 6) : 0;
    const int thi = ty ? n_tiles : ((T0 + 63) >> 6);
    const int lo = ty ? T0 : 0;
    const int hi = ty ? M : T0;
    const int range = thi - tlo;
    const int per = (range + half - 1) / half;
    const int c0 = tlo + bi * per;
    const int c1 = min(c0 + per, thi);

    // ---- register B fragments + biases for this block's type (static idx) ----
    short8 Bf1[4][4], Bf2[2][4];
    float b1r[4], b2r[4];
#pragma unroll
    for (int ni = 0; ni < 4; ++ni) {
        const int c = ni * 16 + l15;
        b1r[ni] = b1[ty * 64 + c];
        b2r[ni] = b2[ty * 64 + c];
#pragma unroll
        for (int s = 0; s < 4; ++s) {
            U8 tmp;
            const float* wp = w1 + (size_t)ty * 8192 + (size_t)(s * 32 + quad * 8) * 64 + c;
#pragma unroll
            for (int jp = 0; jp < 4; ++jp) tmp.u[jp] = pk(wp[(2 * jp) * 64], wp[(2 * jp + 1) * 64]);
            Bf1[s][ni] = tmp.v;
        }
#pragma unroll
        for (int s = 0; s < 2; ++s) {
            U8 tmp;
            const float* wp = w2 + (size_t)ty * 4096 + (size_t)(s * 32 + quad * 8) * 64 + c;
#pragma unroll
            for (int jp = 0; jp < 4; ++jp) tmp.u[jp] = pk(wp[(2 * jp) * 64], wp[(2 * jp + 1) * 64]);
            Bf2[s][ni] = tmp.v;
        }
    }

    u16* hid = sHid[wv];
    u16* msg = sMsg[wv];

    int t = c0 + wv;
    int mdc = -1;            // dst vector for current tile (lane l = edge l)
    int msn = 0, mdn = -1;   // meta for tile t+4
    short8 a1[4][4];
    if (t < c1) {  // prologue: tile-t meta + gathers, tile-(t+4) meta
        int ec = min((t << 6) + l, M - 1);
        int ms = srcP[ec];
        mdc = dstP[ec];
#pragma unroll
        for (int mi = 0; mi < 4; ++mi) {
            int rs = __shfl(ms, mi * 16 + l15);
            int rd = __shfl(mdc, mi * 16 + l15);
#pragma unroll
            for (int s = 0; s < 4; ++s) {
                const int row = (s < 2) ? rs : rd;
                a1[mi][s] = *(const short8*)(hbf + (size_t)row * 64 + (s & 1) * 32 + quad * 8);
            }
        }
        int ecn = min(((t + 4) << 6) + l, M - 1);
        msn = srcP[ecn];
        mdn = dstP[ecn];
    }

    for (; t < c1; t += 4) {
        const int base = t << 6;
        // meta prefetch for t+8 (clamped; harmless past end)
        const int ecf = min(((t + 8) << 6) + l, M - 1);
        const int msf = srcP[ecf];
        const int mdf = dstP[ecf];

        // ---- layer 1 with fused next-tile (t+4) A-gathers ----
#pragma unroll
        for (int mi = 0; mi < 4; ++mi) {
            f32x4 acc[4] = {vz, vz, vz, vz};
#pragma unroll
            for (int s = 0; s < 4; ++s)
#pragma unroll
                for (int ni = 0; ni < 4; ++ni)
                    acc[ni] = __builtin_amdgcn_mfma_f32_16x16x32_bf16(a1[mi][s], Bf1[s][ni], acc[ni], 0, 0, 0);
            // a1[mi] consumed -> issue next tile's gathers for this mi now
            {
                int rs = __shfl(msn, mi * 16 + l15);
                int rd = __shfl(mdn, mi * 16 + l15);
#pragma unroll
                for (int s = 0; s < 4; ++s) {
                    const int row = (s < 2) ? rs : rd;
                    a1[mi][s] = *(const short8*)(hbf + (size_t)row * 64 + (s & 1) * 32 + quad * 8);
                }
            }
#pragma unroll
            for (int ni = 0; ni < 4; ++ni) {
                const int c = ni * 16 + l15;
#pragma unroll
                for (int r = 0; r < 4; ++r) {
                    float hv = fmaxf(acc[ni][r] + b1r[ni], 0.f);
                    hid[(mi * 16 + quad * 4 + r) * 72 + c] = (u16)f2bf_fast(hv);
                }
            }
        }

        // ---- layer 2 ----
#pragma unroll
        for (int mi = 0; mi < 4; ++mi) {
            short8 a2a = *(const short8*)(hid + (mi * 16 + l15) * 72 + quad * 8);
            short8 a2b = *(const short8*)(hid + (mi * 16 + l15) * 72 + 32 + quad * 8);
#pragma unroll
            for (int ni = 0; ni < 4; ++ni) {
                f32x4 tt = __builtin_amdgcn_mfma_f32_16x16x32_bf16(a2a, Bf2[0][ni], vz, 0, 0, 0);
                f32x4 m2 = __builtin_amdgcn_mfma_f32_16x16x32_bf16(a2b, Bf2[1][ni], tt, 0, 0, 0);
                const int c = ni * 16 + l15;
                const int e0 = mi * 16 + quad * 4;
                const float bb = b2r[ni];
                uint2 w;
                w.x = pk_fast(m2[0] + bb, m2[1] + bb);
                w.y = pk_fast(m2[2] + bb, m2[3] + bb);
                *(uint2*)(msg + c * 76 + e0) = w;  // 8B-aligned (c*152 + e0*2)
            }
        }

        // ---- run-reduction: ballot mask in SGPRs, one f32 atomic per (run, col) ----
        {
            int eg = base + l;
            int dvz = (eg >= lo && eg < hi) ? mdc : -1;
            int dprev = __shfl_up(dvz, 1);
            u64 mask = __ballot((l == 0) || (dvz != dprev));
            float a = 0.f;
#pragma unroll
            for (int i = 0; i < 64; i += 4) {
                uint2 pr = *(const uint2*)(msg + l * 76 + i);
                float v0 = bflo(pr.x), v1 = bfhi(pr.x), v2 = bflo(pr.y), v3 = bfhi(pr.y);
#define RR_STEP(ii, vv)                                                         \
                a += (vv);                                                      \
                if ((ii) == 63 || ((mask >> ((ii) + 1)) & 1ull)) {              \
                    int dd = __builtin_amdgcn_readlane(dvz, (ii));              \
                    if (dd >= 0) unsafeAtomicAdd(agg + (size_t)dd * 64 + l, a); \
                    a = 0.f;                                                    \
                }
                RR_STEP(i, v0)
                RR_STEP(i + 1, v1)
                RR_STEP(i + 2, v2)
                RR_STEP(i + 3, v3)
#undef RR_STEP
            }
        }
        // rotate meta pipeline
        mdc = mdn;
        msn = msf;
        mdn = mdf;
    }
}

// ---------- GRU via MFMA (fp32 agg, bf16 state), fused readout on last layer ----------
__global__ __launch_bounds__(256, 2) void k_gru_gemm(
    float* __restrict__ agg, u16* __restrict__ hbf,
    const float* __restrict__ wi, const float* __restrict__ wh,
    const float* __restrict__ bi, const float* __restrict__ bh, int n_nodes, int last,
    const float* __restrict__ ro_w1, const float* __restrict__ ro_b1,
    const float* __restrict__ ro_w2, const float* __restrict__ ro_b2,
    const float* __restrict__ x, const int* __restrict__ node_type, float* __restrict__ out) {
    extern __shared__ u16 smem[];
    u16* sRZ = smem;                 // 128 cols x stride 136 (r|z), K=128=[agg|h]
    u16* sIN = smem + 128 * 136;     // 64 cols x stride 72, K=64 (agg)
    u16* sHN = sIN + 64 * 72;        // 64 cols x stride 72, K=64 (h)
    u16* sTR = sHN + 64 * 72;        // 4 waves x (16 nodes x stride 72) output transpose
    u16* sRO = sTR + 4 * 16 * 72;    // readout W1, 64 cols x stride 72

    const int tid = threadIdx.x;
    const int l = tid & 63, wv = tid >> 6;
    const int l15 = l & 15, quad = l >> 4;
    const f32x4 vz = {0.f, 0.f, 0.f, 0.f};

    // stage weights (coalesced: consecutive lanes -> consecutive columns)
    for (int u = tid; u < 128 * 64; u += 256) {
        int c = u & 127, k0 = (u >> 7) * 2;
        float v0 = (k0 < 64) ? wi[k0 * 192 + c] : wh[(k0 - 64) * 192 + c];
        float v1 = (k0 < 64) ? wi[(k0 + 1) * 192 + c] : wh[(k0 + 1 - 64) * 192 + c];
        *(u32*)(sRZ + c * 136 + k0) = pk(v0, v1);
    }
    for (int u = tid; u < 64 * 32; u += 256) {
        int c = u & 63, k0 = (u >> 6) * 2;
        *(u32*)(sIN + c * 72 + k0) = pk(wi[k0 * 192 + 128 + c], wi[(k0 + 1) * 192 + 128 + c]);
        *(u32*)(sHN + c * 72 + k0) = pk(wh[k0 * 192 + 128 + c], wh[(k0 + 1) * 192 + 128 + c]);
        *(u32*)(sRO + c * 72 + k0) = pk(ro_w1[k0 * 64 + c], ro_w1[(k0 + 1) * 64 + c]);
    }
    float bR[4], bZ[4], bI[4], bH[4], b1v[4], w2v[4];
#pragma unroll
    for (int nt = 0; nt < 4; ++nt) {
        int j = nt * 16 + l15;
        bR[nt] = bi[j] + bh[j];
        bZ[nt] = bi[64 + j] + bh[64 + j];
        bI[nt] = bi[128 + j];
        bH[nt] = bh[128 + j];
        b1v[nt] = ro_b1[j];
        w2v[nt] = ro_w2[j];
    }
    const float b2s = ro_b2[0];
    __syncthreads();  // the only barrier

    u16* tr = sTR + wv * (16 * 72);
    const f32x4 z4 = {0.f, 0.f, 0.f, 0.f};
    const int n_tiles = (n_nodes + 15) >> 4;
    // XCD-chunked node ranges: group g owns a contiguous eighth of the tiles
    const int g = blockIdx.x & 7, jb = blockIdx.x >> 3, nbg = gridDim.x >> 3;
    const int per8 = (n_tiles + 7) >> 3;
    const int glo = g * per8, ghi = min(glo + per8, n_tiles);
    for (int tile = glo + jb * 4 + wv; tile < ghi; tile += nbg * 4) {
        const int nb = tile << 4;
        const int arow = nb + l15;
        const int rowc = (arow < n_nodes) ? arow : (n_nodes - 1);
        short8 aA[2], aH[2];
#pragma unroll
        for (int s = 0; s < 2; ++s) {
            const float* ap = agg + (size_t)rowc * 64 + s * 32 + quad * 8;
            U8 tt;
#pragma unroll
            for (int jp = 0; jp < 4; ++jp) tt.u[jp] = pk(ap[2 * jp], ap[2 * jp + 1]);
            aA[s] = tt.v;
            aH[s] = *(const short8*)(hbf + (size_t)rowc * 64 + s * 32 + quad * 8);
        }
        // re-zero agg for the next layer (tile rows exclusively ours; skip on last)
        if (!last && arow < n_nodes) {
#pragma unroll
            for (int s = 0; s < 2; ++s) {
                *(f32x4*)(agg + (size_t)rowc * 64 + s * 32 + quad * 8) = z4;
                *(f32x4*)(agg + (size_t)rowc * 64 + s * 32 + quad * 8 + 4) = z4;
            }
        }
        f32x4 D[16];
#pragma unroll
        for (int i = 0; i < 16; ++i) D[i] = vz;
#pragma unroll
        for (int nt = 0; nt < 8; ++nt) {
            const u16* bp = sRZ + (nt * 16 + l15) * 136 + quad * 8;
            D[nt] = __builtin_amdgcn_mfma_f32_16x16x32_bf16(aA[0], *(const short8*)bp, D[nt], 0, 0, 0);
            D[nt] = __builtin_amdgcn_mfma_f32_16x16x32_bf16(aA[1], *(const short8*)(bp + 32), D[nt], 0, 0, 0);
            D[nt] = __builtin_amdgcn_mfma_f32_16x16x32_bf16(aH[0], *(const short8*)(bp + 64), D[nt], 0, 0, 0);
            D[nt] = __builtin_amdgcn_mfma_f32_16x16x32_bf16(aH[1], *(const short8*)(bp + 96), D[nt], 0, 0, 0);
        }
#pragma unroll
        for (int nt = 0; nt < 4; ++nt) {
            const u16* ip = sIN + (nt * 16 + l15) * 72 + quad * 8;
            D[8 + nt] = __builtin_amdgcn_mfma_f32_16x16x32_bf16(aA[0], *(const short8*)ip, D[8 + nt], 0, 0, 0);
            D[8 + nt] = __builtin_amdgcn_mfma_f32_16x16x32_bf16(aA[1], *(const short8*)(ip + 32), D[8 + nt], 0, 0, 0);
            const u16* hp = sHN + (nt * 16 + l15) * 72 + quad * 8;
            D[12 + nt] = __builtin_amdgcn_mfma_f32_16x16x32_bf16(aH[0], *(const short8*)hp, D[12 + nt], 0, 0, 0);
            D[12 + nt] = __builtin_amdgcn_mfma_f32_16x16x32_bf16(aH[1], *(const short8*)(hp + 32), D[12 + nt], 0, 0, 0);
        }
        // combine -> per-wave LDS transpose tile (u16), then coalesced global stores
#pragma unroll
        for (int nt = 0; nt < 4; ++nt) {
            const int j = nt * 16 + l15;
#pragma unroll
            for (int r = 0; r < 4; ++r) {
                const int nd = nb + quad * 4 + r;
                float rsv = D[nt][r] + bR[nt];
                float zsv = D[4 + nt][r] + bZ[nt];
                float inv = D[8 + nt][r] + bI[nt];
                float hnv = D[12 + nt][r] + bH[nt];
                float rr = 1.f / (1.f + __expf(-rsv));
                float zz = 1.f / (1.f + __expf(-zsv));
                float nn = tanhf(fmaf(rr, hnv, inv));
                float hv = (nd < n_nodes) ? bfu(hbf[(size_t)nd * 64 + j]) : 0.f;
                float nh = (1.f - zz) * nn + zz * hv;
                tr[(quad * 4 + r) * 72 + j] = (u16)f2bf(nh);
            }
        }
        {   // coalesced write-back: lane covers 32 contiguous bytes of one node
            const int nd = nb + (l >> 2);
            if (nd < n_nodes) {
                const u16* sp = tr + (l >> 2) * 72 + (l & 3) * 16;
                uint4 va = *(const uint4*)sp;
                uint4 vb = *(const uint4*)(sp + 8);
                u16* dp = hbf + (size_t)nd * 64 + (l & 3) * 16;
                *(uint4*)dp = va;
                *(uint4*)(dp + 8) = vb;
            }
        }
        if (last) {  // fused readout: tr holds this tile's final h (same-wave DS order)
            short8 ar0 = *(const short8*)(tr + l15 * 72 + quad * 8);
            short8 ar1 = *(const short8*)(tr + l15 * 72 + 32 + quad * 8);
            float p[4] = {0.f, 0.f, 0.f, 0.f};
#pragma unroll
            for (int nt = 0; nt < 4; ++nt) {
                const u16* bp = sRO + (nt * 16 + l15) * 72 + quad * 8;
                f32x4 acc = __builtin_amdgcn_mfma_f32_16x16x32_bf16(ar0, *(const short8*)bp, vz, 0, 0, 0);
                acc = __builtin_amdgcn_mfma_f32_16x16x32_bf16(ar1, *(const short8*)(bp + 32), acc, 0, 0, 0);
#pragma unroll
                for (int r = 0; r < 4; ++r)
                    p[r] += fmaxf(acc[r] + b1v[nt], 0.f) * w2v[nt];
            }
#pragma unroll
            for (int off = 1; off < 16; off <<= 1)
#pragma unroll
                for (int r = 0; r < 4; ++r) p[r] += __shfl_xor(p[r], off);
            if (l15 == 0) {
#pragma unroll
                for (int r = 0; r < 4; ++r) {
                    const int nd = nb + quad * 4 + r;
                    if (nd < n_nodes) {
                        float o = p[r] + b2s;
                        out[nd] = (node_type[nd] == 0) ? (x[nd * 4] + o) : 0.f;
                    }
                }
            }
        }
    }
}

extern "C" void kernel_launch(void* const* d_in, const int* in_sizes, int n_in, void* d_out,
                              int out_size, void* d_ws, size_t ws_size, hipStream_t stream) {
    const float* x = (const float*)d_in[0];
    const int* node_type = (const int*)d_in[1];
    const int* edge_index = (const int*)d_in[2];
    const int* edge_type = (const int*)d_in[3];
    const float* in_w = (const float*)d_in[4];
    const float* in_b = (const float*)d_in[5];
    const float* ln_g = (const float*)d_in[6];
    const float* ln_b = (const float*)d_in[7];
    const float* mlp_w1 = (const float*)d_in[8];
    const float* mlp_b1 = (const float*)d_in[9];
    const float* mlp_w2 = (const float*)d_in[10];
    const float* mlp_b2 = (const float*)d_in[11];
    const float* gru_wi = (const float*)d_in[12];
    const float* gru_wh = (const float*)d_in[13];
    const float* gru_bi = (const float*)d_in[14];
    const float* gru_bh = (const float*)d_in[15];
    const float* ro_w1 = (const float*)d_in[16];
    const float* ro_b1 = (const float*)d_in[17];
    const float* ro_w2 = (const float*)d_in[18];
    const float* ro_b2 = (const float*)d_in[19];

    const int N = in_sizes[1];  // nodes
    const int M = in_sizes[3];  // edges
    const int* src = edge_index;
    const int* dst = edge_index + M;

    // ws: agg fp32 (N*256B) | hbf (N*128B) | off (2N*4) | part (4KB) | srcP | dstP | key
    char* wsb = (char*)d_ws;
    float* agg = (float*)wsb;
    u16* hbf = (u16*)(wsb + (size_t)N * 256);
    int* off = (int*)(wsb + (size_t)N * 384);
    int* part = (int*)(wsb + (size_t)N * 384 + (size_t)2 * N * 4);
    int* srcP = (int*)(wsb + (size_t)N * 384 + (size_t)2 * N * 4 + 4096);
    int* dstP = srcP + M;
    int* key = dstP + M;
    int* t0slot = part + 1000;

    const int NB = 2 * N;
    const int nb = (NB + 1023) / 1024;
    const int nd8 = (N + 7) / 8;

    // build (type,dst)-sorted edge permutation (reused by all 3 layers)
    hipMemsetAsync(off, 0, (size_t)NB * sizeof(int), stream);
    k_hist<<<(M + 255) / 256, 256, 0, stream>>>(dst, edge_type, off, key, M, N);
    k_scan1<<<nb, 1024, 0, stream>>>(off, part, NB);
    k_scan2<<<1, 64, 0, stream>>>(part, nb);
    k_scan3<<<nb, 1024, 0, stream>>>(off, part, NB, N, t0slot);
    k_filldst<<<(NB + 255) / 256, 256, 0, stream>>>(off, dstP, NB, N, M);  // before cursors mutate
    k_scatter<<<2048, 256, 0, stream>>>(src, key, off, srcP, M, N, nd8);

    k_input_proj<<<(N + 3) / 4, 256, 0, stream>>>(x, in_w, in_b, ln_g, ln_b, hbf, agg, N);
    const size_t gruLds =
        (size_t)(128 * 136 + 64 * 72 + 64 * 72 + 4 * 16 * 72 + 64 * 72) * sizeof(u16);  // 71680
    for (int l = 0; l < 3; ++l) {
        k_edge_mlp<<<1024, 256, 0, stream>>>(hbf, srcP, dstP, t0slot,
                                             mlp_w1 + (size_t)l * 2 * 128 * 64,
                                             mlp_b1 + (size_t)l * 2 * 64,
                                             mlp_w2 + (size_t)l * 2 * 64 * 64,
                                             mlp_b2 + (size_t)l * 2 * 64, agg, M);
        k_gru_gemm<<<1024, 256, gruLds, stream>>>(agg, hbf, gru_wi + (size_t)l * 64 * 192,
                                                  gru_wh + (size_t)l * 64 * 192,
                                                  gru_bi + (size_t)l * 192, gru_bh + (size_t)l * 192,
                                                  N, (l == 2) ? 1 : 0,
                                                  ro_w1, ro_b1, ro_w2, ro_b2,
                                                  x, node_type, (float*)d_out);
    }
}